// Round 3
// baseline (628.787 us; speedup 1.0000x reference)
//
#include <hip/hip_runtime.h>

typedef unsigned short u16;
typedef __attribute__((ext_vector_type(4))) float floatx4;
typedef __attribute__((ext_vector_type(8))) __bf16 bf16x8;
typedef __attribute__((ext_vector_type(4))) unsigned short ushort4v;
typedef __attribute__((ext_vector_type(8))) unsigned short ushort8v;

#define DI __device__ __forceinline__

// ---- problem constants ----
// B=8, C=512, T=1024, H=8, F=2048, KS=3, head dim 64, ROPE_D=32, EPS=1e-4

DI u16 f2bf(float f) {
  union { float f; unsigned u; } v; v.f = f;
  unsigned r = v.u + 0x7fffu + ((v.u >> 16) & 1u);
  return (u16)(r >> 16);
}
DI float bf2f(u16 h) {
  union { unsigned u; float f; } v; v.u = ((unsigned)h) << 16;
  return v.f;
}

#define GLDS(g, l) __builtin_amdgcn_global_load_lds( \
    (const __attribute__((address_space(1))) unsigned int*)(g), \
    (__attribute__((address_space(3))) unsigned int*)(l), 16, 0, 0)

// ---------------------------------------------------------------------------
// Batched bf16 MFMA GEMM (z = batch*head), gemm_bt form, BK=64 (2 half-tiles).
// MODE 1 = scores (scale + bit-mask, bf16 out), MODE 2 = PV (write o^T (B,T,C))
// ---------------------------------------------------------------------------
template<int MODE, int BN>
__global__ __launch_bounds__(256) void k_gemm(
    const u16* __restrict__ A, int lda, long long sAz,
    const u16* __restrict__ Bt, int ldb, long long sBz,
    int K,
    u16* __restrict__ o0,
    const unsigned* __restrict__ mb)
{
  constexpr int BM = 128;
  constexpr int FN = BN / 32;
  __shared__ __align__(16) u16 As[2 * BM * 32];
  __shared__ __align__(16) u16 Bs[2 * BN * 32];

  const int tid  = threadIdx.x;
  const int wave = tid >> 6, lane = tid & 63;
  const int wm = wave >> 1, wn = wave & 1;
  const int lr = lane & 15, kg = lane >> 4;
  const int m0 = blockIdx.x * BM, n0 = blockIdx.y * BN;
  const int z  = blockIdx.z;
  const u16* Ab = A  + (size_t)z * sAz;
  const u16* Bb = Bt + (size_t)z * sBz;

  floatx4 acc[4][FN];
#pragma unroll
  for (int i = 0; i < 4; ++i)
#pragma unroll
    for (int j = 0; j < FN; ++j) acc[i][j] = (floatx4){0.f, 0.f, 0.f, 0.f};

  for (int k0 = 0; k0 < K; k0 += 64) {
#pragma unroll
    for (int h = 0; h < 2; ++h) {
#pragma unroll
      for (int ch = 0; ch < BM / 64; ++ch) {
        int idx = ch * 256 + tid;
        int row = idx >> 2, kk = (idx & 3) << 3;
        GLDS(Ab + (size_t)(m0 + row) * lda + (k0 + h * 32 + kk),
             &As[h * BM * 32 + idx * 8]);
      }
#pragma unroll
      for (int ch = 0; ch < BN / 64; ++ch) {
        int idx = ch * 256 + tid;
        int row = idx >> 2, kk = (idx & 3) << 3;
        GLDS(Bb + (size_t)(n0 + row) * ldb + (k0 + h * 32 + kk),
             &Bs[h * BN * 32 + idx * 8]);
      }
    }
    __syncthreads();
    bf16x8 af[2][4], bfr[2][FN];
#pragma unroll
    for (int h = 0; h < 2; ++h) {
#pragma unroll
      for (int i = 0; i < 4; ++i)
        af[h][i] = *(const bf16x8*)&As[(h * BM + wm * 64 + i * 16 + lr) * 32 + kg * 8];
#pragma unroll
      for (int j = 0; j < FN; ++j)
        bfr[h][j] = *(const bf16x8*)&Bs[(h * BN + wn * (BN / 2) + j * 16 + lr) * 32 + kg * 8];
    }
#pragma unroll
    for (int h = 0; h < 2; ++h)
#pragma unroll
      for (int i = 0; i < 4; ++i)
#pragma unroll
        for (int j = 0; j < FN; ++j)
          acc[i][j] = __builtin_amdgcn_mfma_f32_16x16x32_bf16(af[h][i], bfr[h][j], acc[i][j], 0, 0, 0);
    __syncthreads();
  }

  const int wrow0 = m0 + wm * 64;
  const int col0  = n0 + wn * (BN / 2);

  if constexpr (MODE == 1) {  // ---- scores: *1/8, bit-mask, bf16 ----
    const int bb = z >> 3;
#pragma unroll
    for (int i = 0; i < 4; ++i)
#pragma unroll
      for (int j = 0; j < FN; ++j) {
        const int cc = col0 + j * 16 + lr;
#pragma unroll
        for (int r = 0; r < 4; ++r) {
          const int rr = wrow0 + i * 16 + kg * 4 + r;
          float sv = acc[i][j][r] * 0.125f;
          const unsigned mw = mb[((size_t)bb << 15) + ((size_t)rr << 5) + (cc >> 5)];
          if (!((mw >> (cc & 31)) & 1u)) sv = -10000.f;
          o0[((size_t)z * 1024 + rr) * 1024 + cc] = f2bf(sv);
        }
      }
  } else {                    // ---- PV: write o^T (B,T,C) ----
    const int bb = z >> 3, hh = z & 7;
#pragma unroll
    for (int i = 0; i < 4; ++i)
#pragma unroll
      for (int j = 0; j < FN; ++j) {
        const int dk = col0 + j * 16 + lr;
#pragma unroll
        for (int r = 0; r < 4; ++r) {
          const int t = wrow0 + i * 16 + kg * 4 + r;
          o0[((size_t)bb * 1024 + t) * 512 + hh * 64 + dk] = f2bf(acc[i][j][r]);
        }
      }
  }
}

// ---------------------------------------------------------------------------
// Flat GEMM (batch folded into N=8192), gemm_bt form, XCD-swizzled, BK=64.
// A (M x Ktot) row-major, lda = row stride. K = this block's K-slice length;
// koff = blockIdx.z * K (split-K via grid z, MODE 5 only).
//   TAPK == 0 : Bt row bt, row stride ldb
//   TAPK > 0  : conv tap mode — B[bt, k] = Bpad[b, t + k/TAPK, k%TAPK],
//               Bpad (B, 1026, TAPK) zero-padded rows 0 / 1025.
// MODE 0=QKV(+bias+rope+scatter) 3=oproj(+bias) 4=conv1(relu*mask -> padded h1)
// MODE 5=conv2(split-K partials, +bias on z0, *mask)
// ---------------------------------------------------------------------------
template<int MODE, int BN, int TAPK>
__global__ __launch_bounds__(256) void k_cgemm(
    const u16* __restrict__ A, int lda,
    const u16* __restrict__ Bsrc, int ldb,
    int K,
    u16* __restrict__ o0, u16* __restrict__ o1, u16* __restrict__ o2,
    const float* __restrict__ bias,
    const float* __restrict__ ctab, const float* __restrict__ stab,
    const float* __restrict__ msk)
{
  constexpr int BM = 128;
  constexpr int FN = BN / 32;
  __shared__ __align__(16) u16 As[2 * BM * 32];
  __shared__ __align__(16) u16 Bs[2 * BN * 32];

  const int tid  = threadIdx.x;
  const int wave = tid >> 6, lane = tid & 63;
  const int wm = wave >> 1, wn = wave & 1;
  const int lr = lane & 15, kg = lane >> 4;

  // XCD-aware bijective swizzle (nwg % 8 == 0 for all our grids)
  const int nwg = gridDim.x * gridDim.y;
  const int h0  = blockIdx.y * gridDim.x + blockIdx.x;
  const int cpx = nwg >> 3;
  const int tl  = (h0 & 7) * cpx + (h0 >> 3);
  const int bx  = tl % gridDim.x;
  const int by  = tl / gridDim.x;

  const int m0 = bx * BM, n0 = by * BN;
  const int koff = blockIdx.z * K;

  floatx4 acc[4][FN];
#pragma unroll
  for (int i = 0; i < 4; ++i)
#pragma unroll
    for (int j = 0; j < FN; ++j) acc[i][j] = (floatx4){0.f, 0.f, 0.f, 0.f};

  for (int k0 = 0; k0 < K; k0 += 64) {
#pragma unroll
    for (int h = 0; h < 2; ++h) {
      const int kglob = koff + k0 + h * 32;
#pragma unroll
      for (int ch = 0; ch < BM / 64; ++ch) {
        int idx = ch * 256 + tid;
        int row = idx >> 2, kk = (idx & 3) << 3;
        GLDS(A + (size_t)(m0 + row) * lda + (kglob + kk),
             &As[h * BM * 32 + idx * 8]);
      }
#pragma unroll
      for (int ch = 0; ch < BN / 64; ++ch) {
        int idx = ch * 256 + tid;
        int row = idx >> 2, kk = (idx & 3) << 3;
        const int bt = n0 + row;
        const u16* src;
        if constexpr (TAPK == 0) {
          src = Bsrc + (size_t)bt * ldb + (kglob + kk);
        } else {
          const int tap = kglob / TAPK, off2 = kglob - tap * TAPK;
          const int b = bt >> 10, t = bt & 1023;
          src = Bsrc + ((size_t)(b * 1026 + t + tap)) * TAPK + off2 + kk;
        }
        GLDS(src, &Bs[h * BN * 32 + idx * 8]);
      }
    }
    __syncthreads();
    bf16x8 af[2][4], bfr[2][FN];
#pragma unroll
    for (int h = 0; h < 2; ++h) {
#pragma unroll
      for (int i = 0; i < 4; ++i)
        af[h][i] = *(const bf16x8*)&As[(h * BM + wm * 64 + i * 16 + lr) * 32 + kg * 8];
#pragma unroll
      for (int j = 0; j < FN; ++j)
        bfr[h][j] = *(const bf16x8*)&Bs[(h * BN + wn * (BN / 2) + j * 16 + lr) * 32 + kg * 8];
    }
#pragma unroll
    for (int h = 0; h < 2; ++h)
#pragma unroll
      for (int i = 0; i < 4; ++i)
#pragma unroll
        for (int j = 0; j < FN; ++j)
          acc[i][j] = __builtin_amdgcn_mfma_f32_16x16x32_bf16(af[h][i], bfr[h][j], acc[i][j], 0, 0, 0);
    __syncthreads();
  }

  const int wrow0 = m0 + wm * 64;
  const int col0  = n0 + wn * (BN / 2);

  if constexpr (MODE == 0) {  // ---- QKV: bias + RoPE + scatter ----
    float v[4][FN][4];
#pragma unroll
    for (int i = 0; i < 4; ++i)
#pragma unroll
      for (int j = 0; j < FN; ++j)
#pragma unroll
        for (int r = 0; r < 4; ++r)
          v[i][j][r] = acc[i][j][r] + bias[wrow0 + i * 16 + kg * 4 + r];
    const int sec = wrow0 >> 9;            // 0=q 1=k 2=v
    const int hh  = (wrow0 & 511) >> 6;    // head
    if (sec < 2) {
#pragma unroll
      for (int j = 0; j < FN; ++j) {
        const int t = (col0 + j * 16 + lr) & 1023;
#pragma unroll
        for (int r = 0; r < 4; ++r) {
          const int a = kg * 4 + r;
          const float cv = ctab[t * 16 + a], sv = stab[t * 16 + a];
          const float a0 = v[0][j][r], a1 = v[1][j][r];
          v[0][j][r] = a0 * cv - a1 * sv;
          v[1][j][r] = a1 * cv + a0 * sv;
        }
      }
      u16* dst = (sec == 0) ? o0 : o1;     // q,k: (B,H,T,64)
#pragma unroll
      for (int i = 0; i < 4; ++i)
#pragma unroll
        for (int j = 0; j < FN; ++j) {
          const int bt = col0 + j * 16 + lr;
          const int b = bt >> 10, t = bt & 1023;
          ushort4v pk;
#pragma unroll
          for (int r = 0; r < 4; ++r) pk[r] = f2bf(v[i][j][r]);
          *(ushort4v*)&dst[(((size_t)b * 8 + hh) * 1024 + t) * 64 + i * 16 + kg * 4] = pk;
        }
    } else {                               // v: (B,H,64,T)
#pragma unroll
      for (int i = 0; i < 4; ++i)
#pragma unroll
        for (int j = 0; j < FN; ++j) {
          const int bt = col0 + j * 16 + lr;
          const int b = bt >> 10, t = bt & 1023;
#pragma unroll
          for (int r = 0; r < 4; ++r) {
            const int dk = i * 16 + kg * 4 + r;
            o2[(((size_t)b * 8 + hh) * 64 + dk) * 1024 + t] = f2bf(v[i][j][r]);
          }
        }
    }
  } else if constexpr (MODE == 3) {  // ---- O-proj: +bias -> y (B,C,T) bf16 ----
#pragma unroll
    for (int i = 0; i < 4; ++i)
#pragma unroll
      for (int j = 0; j < FN; ++j) {
        const int bt = col0 + j * 16 + lr;
        const int b = bt >> 10, t = bt & 1023;
#pragma unroll
        for (int r = 0; r < 4; ++r) {
          const int rr = wrow0 + i * 16 + kg * 4 + r;
          o0[((size_t)b * 512 + rr) * 1024 + t] = f2bf(acc[i][j][r] + bias[rr]);
        }
      }
  } else if constexpr (MODE == 4) {  // ---- conv1: relu(acc+b1)*mask -> h1pad ----
#pragma unroll
    for (int i = 0; i < 4; ++i) {
      const int r0 = wrow0 + i * 16 + kg * 4;
#pragma unroll
      for (int j = 0; j < FN; ++j) {
        const int bt = col0 + j * 16 + lr;
        const int b = bt >> 10, t = bt & 1023;
        const float mv = msk[(size_t)b * 1024 + t];
        ushort4v pk;
#pragma unroll
        for (int r = 0; r < 4; ++r)
          pk[r] = f2bf(fmaxf(acc[i][j][r] + bias[r0 + r], 0.f) * mv);
        *(ushort4v*)&o0[((size_t)(b * 1026 + t + 1)) * 2048 + r0] = pk;
      }
    }
  } else {                           // ---- conv2 split-K partial -> y (B,C,T) ----
    u16* dst = (blockIdx.z == 0) ? o0 : o1;
#pragma unroll
    for (int i = 0; i < 4; ++i)
#pragma unroll
      for (int j = 0; j < FN; ++j) {
        const int bt = col0 + j * 16 + lr;
        const int b = bt >> 10, t = bt & 1023;
        const float mv = msk[(size_t)b * 1024 + t];
#pragma unroll
        for (int r = 0; r < 4; ++r) {
          const int rr = wrow0 + i * 16 + kg * 4 + r;
          const float bv = (blockIdx.z == 0) ? bias[rr] : 0.f;
          dst[((size_t)b * 512 + rr) * 1024 + t] = f2bf((acc[i][j][r] + bv) * mv);
        }
      }
  }
}

// ---------------------------------------------------------------------------
// glue kernels
// ---------------------------------------------------------------------------
__global__ __launch_bounds__(256) void k_cvt(const float* __restrict__ in, u16* __restrict__ out, int n) {
  int i = blockIdx.x * 256 + threadIdx.x;
  if (i < n) out[i] = f2bf(in[i]);
}

__global__ __launch_bounds__(256) void k_repack_w1(const float* __restrict__ in, u16* __restrict__ out) {
  int i = blockIdx.x * 256 + threadIdx.x;          // over 2048*1536
  int f = i / 1536, rem = i % 1536;
  int kk = rem >> 9, c = rem & 511;                // out (F, KS, C)
  out[i] = f2bf(in[f * 1536 + c * 3 + kk]);
}

__global__ __launch_bounds__(256) void k_repack_w2(const float* __restrict__ in, u16* __restrict__ out) {
  int i = blockIdx.x * 256 + threadIdx.x;          // over 512*6144
  int c = i / 6144, rem = i % 6144;
  int kk = rem >> 11, f = rem & 2047;              // out (C, KS, F)
  out[i] = f2bf(in[c * 6144 + f * 3 + kk]);
}

__global__ __launch_bounds__(256) void k_bias_concat(const float* __restrict__ bq, const float* __restrict__ bk,
                                                     const float* __restrict__ bv, float* __restrict__ out) {
  int i = blockIdx.x * 256 + threadIdx.x;
  if (i < 512) out[i] = bq[i];
  else if (i < 1024) out[i] = bk[i - 512];
  else if (i < 1536) out[i] = bv[i - 1024];
}

__global__ __launch_bounds__(256) void k_rope_tables(float* __restrict__ ct, float* __restrict__ st) {
  int i = blockIdx.x * 256 + threadIdx.x;          // 1024*16
  int t = i >> 4, a = i & 15;
  float theta = powf(10000.f, -(float)a / 16.f);
  float ang = (float)t * theta;
  ct[i] = cosf(ang);
  st[i] = sinf(ang);
}

// pack attn_mask (B,1,T,T) fp32 -> bits; word i covers cols [i*32, i*32+32)
__global__ __launch_bounds__(256) void k_maskpack(const float* __restrict__ am, unsigned* __restrict__ mb) {
  int i = blockIdx.x * 256 + threadIdx.x;          // 8*1024*32 words
  const float* src = am + (size_t)i * 32;
  unsigned w = 0;
#pragma unroll
  for (int q = 0; q < 32; ++q) w |= (src[q] != 0.f) ? (1u << q) : 0u;
  mb[i] = w;
}

// zero pad rows (row 0 and 1025 of each batch) of a (B,1026,R) bf16 buffer
__global__ __launch_bounds__(256) void k_zrows(u16* __restrict__ p, int R) {
  const int b = blockIdx.x >> 1;
  const size_t row = (blockIdx.x & 1) ? 1025 : 0;
  u16* r = p + ((size_t)b * 1026 + row) * R;
  for (int i = threadIdx.x; i < R; i += 256) r[i] = 0;
}

// tiled fp32 (B,R,TT) -> bf16 (B, padR, R) transpose-convert at row offset ro,
// optional column mask
__global__ __launch_bounds__(256) void k_tcvt(const float* __restrict__ in, u16* __restrict__ out,
                                              const float* __restrict__ msk, int R, int TT,
                                              int padR, int ro) {
  __shared__ u16 tile[64][65];
  const int b = blockIdx.z;
  const int r0 = blockIdx.x * 64, t0 = blockIdx.y * 64;
  const int tx = threadIdx.x & 63, ty = threadIdx.x >> 6;
  const float mv = msk ? msk[(size_t)b * TT + t0 + tx] : 1.f;
  const float* ib = in + (size_t)b * R * TT;
#pragma unroll
  for (int rr = ty; rr < 64; rr += 4)
    tile[rr][tx] = f2bf(ib[(size_t)(r0 + rr) * TT + t0 + tx] * mv);
  __syncthreads();
  u16* ob = out + (size_t)b * padR * R;
#pragma unroll
  for (int tt = ty; tt < 64; tt += 4)
    ob[(size_t)(t0 + tt + ro) * R + r0 + tx] = tile[tx][tt];
}

// in-place softmax, one WAVE per row of 1024 (no LDS, no barriers)
__global__ __launch_bounds__(256) void k_softmax(u16* __restrict__ s) {
  const int lane = threadIdx.x & 63, wv = threadIdx.x >> 6;
  const size_t row = (size_t)blockIdx.x * 4 + wv;
  u16* p = s + row * 1024;
  ushort8v ua = *(const ushort8v*)&p[lane * 8];
  ushort8v ub = *(const ushort8v*)&p[512 + lane * 8];
  float va[8], vb[8];
  float mx = -3.4e38f;
#pragma unroll
  for (int q = 0; q < 8; ++q) {
    va[q] = bf2f(ua[q]); vb[q] = bf2f(ub[q]);
    mx = fmaxf(mx, fmaxf(va[q], vb[q]));
  }
#pragma unroll
  for (int o = 32; o; o >>= 1) mx = fmaxf(mx, __shfl_xor(mx, o));
  const float L2E = 1.44269504f;
  float sm = 0.f;
#pragma unroll
  for (int q = 0; q < 8; ++q) {
    va[q] = exp2f((va[q] - mx) * L2E);
    vb[q] = exp2f((vb[q] - mx) * L2E);
    sm += va[q] + vb[q];
  }
#pragma unroll
  for (int o = 32; o; o >>= 1) sm += __shfl_xor(sm, o);
  const float inv = 1.f / sm;
  ushort8v oa, ob;
#pragma unroll
  for (int q = 0; q < 8; ++q) { oa[q] = f2bf(va[q] * inv); ob[q] = f2bf(vb[q] * inv); }
  *(ushort8v*)&p[lane * 8] = oa;
  *(ushort8v*)&p[512 + lane * 8] = ob;
}

// layernorm over C=512 at each (b,t); xin fp32 (B,C,T) [*mask], + y bf16 (B,C,T)
// (+ optional second bf16 partial y2)
__global__ __launch_bounds__(256) void k_ln(const float* __restrict__ xin, const u16* __restrict__ ybf,
                                            const u16* __restrict__ y2, const float* __restrict__ xm,
                                            const float* __restrict__ g, const float* __restrict__ be,
                                            float* __restrict__ xout) {
  const int b = blockIdx.x;
  const int tx = threadIdx.x & 63, ty = threadIdx.x >> 6;
  const int t = blockIdx.y * 64 + tx;
  const float m = xm ? xm[(size_t)b * 1024 + t] : 1.f;
  const size_t base = (size_t)b * 512 * 1024 + t;
  float sum = 0.f, ss = 0.f;
  for (int c = ty; c < 512; c += 4) {
    const size_t o = base + (size_t)c * 1024;
    float r = xin[o] * m + bf2f(ybf[o]);
    if (y2) r += bf2f(y2[o]);
    sum += r; ss += r * r;
  }
  __shared__ float S[4][64], Q[4][64];
  S[ty][tx] = sum; Q[ty][tx] = ss;
  __syncthreads();
  sum = S[0][tx] + S[1][tx] + S[2][tx] + S[3][tx];
  ss  = Q[0][tx] + Q[1][tx] + Q[2][tx] + Q[3][tx];
  const float mean = sum * (1.f / 512.f);
  const float var  = ss * (1.f / 512.f) - mean * mean;
  const float rs   = rsqrtf(var + 1e-4f);
  for (int c = ty; c < 512; c += 4) {
    const size_t o = base + (size_t)c * 1024;
    float r = xin[o] * m + bf2f(ybf[o]);
    if (y2) r += bf2f(y2[o]);
    xout[o] = (r - mean) * rs * g[c] + be[c];
  }
}

// ---------------------------------------------------------------------------
extern "C" void kernel_launch(void* const* d_in, const int* in_sizes, int n_in,
                              void* d_out, int out_size, void* d_ws, size_t ws_size,
                              hipStream_t stream) {
  (void)in_sizes; (void)n_in; (void)out_size; (void)ws_size;
  const float* x   = (const float*)d_in[0];
  const float* xm  = (const float*)d_in[1];
  const float* am  = (const float*)d_in[2];
  const float* wq  = (const float*)d_in[3];
  const float* bq  = (const float*)d_in[4];
  const float* wk  = (const float*)d_in[5];
  const float* bk  = (const float*)d_in[6];
  const float* wv  = (const float*)d_in[7];
  const float* bv  = (const float*)d_in[8];
  const float* wo  = (const float*)d_in[9];
  const float* bo  = (const float*)d_in[10];
  const float* w1  = (const float*)d_in[11];
  const float* b1  = (const float*)d_in[12];
  const float* w2  = (const float*)d_in[13];
  const float* b2  = (const float*)d_in[14];
  const float* g1  = (const float*)d_in[15];
  const float* be1 = (const float*)d_in[16];
  const float* g2  = (const float*)d_in[17];
  const float* be2 = (const float*)d_in[18];
  float* out = (float*)d_out;

  char* ws = (char*)d_ws;
  size_t off = 0;
  auto alloc = [&](size_t bytes) { char* p = ws + off; off += (bytes + 255) & ~(size_t)255; return p; };

  u16*   wqkv = (u16*)  alloc((size_t)1536 * 512 * 2);
  u16*   wob  = (u16*)  alloc((size_t)512 * 512 * 2);
  u16*   w1p  = (u16*)  alloc((size_t)2048 * 1536 * 2);
  u16*   w2p  = (u16*)  alloc((size_t)512 * 6144 * 2);
  float* bqkv = (float*)alloc(1536 * 4);
  float* ctab = (float*)alloc(1024 * 16 * 4);
  float* stab = (float*)alloc(1024 * 16 * 4);
  unsigned* mbits = (unsigned*)alloc((size_t)8 * 1024 * 32 * 4);
  float* X2   = (float*)alloc((size_t)8 * 512 * 1024 * 4);   // LN1 output fp32
  u16*   x2p  = (u16*)  alloc((size_t)8 * 1026 * 512 * 2);   // LN1 out ^T, padded, masked
  u16*   h1p  = (u16*)  alloc((size_t)8 * 1026 * 2048 * 2);  // conv1 out, padded (B,1026,F)
  u16*   y    = (u16*)  alloc((size_t)8 * 512 * 1024 * 2);   // y1 then y2 partial A (B,C,T)
  u16*   xbT  = (u16*)  alloc((size_t)8 * 1024 * 512 * 2);   // masked x^T; then o^T; then y2 partial B
  u16*   qkv3 = (u16*)  alloc((size_t)3 * 8 * 8 * 1024 * 64 * 2); // q,k,v
  u16*   sb   = (u16*)  alloc((size_t)8 * 8 * 1024 * 1024 * 2);   // scores / p

  u16* qb  = qkv3;
  u16* kb  = qkv3 + (size_t)8 * 8 * 1024 * 64;
  u16* vb  = kb   + (size_t)8 * 8 * 1024 * 64;
  u16* oT  = xbT;
  u16* y2b = xbT;   // conv2 partial B reuses xbT (dead after O-proj)

  dim3 blk(256);

  // weight/bias/table prep
  k_cvt<<<dim3(1024), blk, 0, stream>>>(wq, wqkv, 512 * 512);
  k_cvt<<<dim3(1024), blk, 0, stream>>>(wk, wqkv + 512 * 512, 512 * 512);
  k_cvt<<<dim3(1024), blk, 0, stream>>>(wv, wqkv + 2 * 512 * 512, 512 * 512);
  k_cvt<<<dim3(1024), blk, 0, stream>>>(wo, wob, 512 * 512);
  k_repack_w1<<<dim3(12288), blk, 0, stream>>>(w1, w1p);
  k_repack_w2<<<dim3(12288), blk, 0, stream>>>(w2, w2p);
  k_bias_concat<<<dim3(6), blk, 0, stream>>>(bq, bk, bv, bqkv);
  k_rope_tables<<<dim3(64), blk, 0, stream>>>(ctab, stab);
  k_maskpack<<<dim3(1024), blk, 0, stream>>>(am, mbits);
  k_zrows<<<dim3(16), blk, 0, stream>>>(x2p, 512);
  k_zrows<<<dim3(16), blk, 0, stream>>>(h1p, 2048);

  // x^T (masked, bf16, unpadded)
  k_tcvt<<<dim3(8, 16, 8), blk, 0, stream>>>(x, xbT, xm, 512, 1024, 1024, 0);

  // QKV projection + bias + rope + head scatter  (flat N=8192)
  k_cgemm<0, 128, 0><<<dim3(12, 64), blk, 0, stream>>>(
      wqkv, 512, xbT, 512, 512, qb, kb, vb, bqkv, ctab, stab, nullptr);

  // scores = q k^T / 8 (+ bit-mask), bf16
  k_gemm<1, 128><<<dim3(8, 8, 64), blk, 0, stream>>>(
      qb, 64, 65536, kb, 64, 65536, 64, sb, mbits);

  // softmax rows in place (wave per row)
  k_softmax<<<dim3(16384), blk, 0, stream>>>(sb);

  // o = p v, written as o^T (B,T,C)
  k_gemm<2, 64><<<dim3(8, 1, 64), blk, 0, stream>>>(
      sb, 1024, 1048576, vb, 1024, 65536, 1024, oT, nullptr);

  // y1 = wo o + bo (B,C,T)
  k_cgemm<3, 64, 0><<<dim3(4, 128), blk, 0, stream>>>(
      wob, 512, oT, 512, 512, y, nullptr, nullptr, bo, nullptr, nullptr, nullptr);

  // LN1: X2 = ln(x*mask + y1)
  k_ln<<<dim3(8, 16), blk, 0, stream>>>(x, y, nullptr, xm, g1, be1, X2);

  // conv path (tap-shifted padded activations, no im2col)
  k_tcvt<<<dim3(8, 16, 8), blk, 0, stream>>>(X2, x2p, xm, 512, 1024, 1026, 1);
  k_cgemm<4, 128, 512><<<dim3(16, 64), blk, 0, stream>>>(
      w1p, 1536, x2p, 0, 1536, h1p, nullptr, nullptr, b1, nullptr, nullptr, xm);
  // conv2: split-K x2 (K-slice 3072 each), partials in y (z0,+bias) and y2b (z1)
  k_cgemm<5, 64, 2048><<<dim3(4, 128, 2), blk, 0, stream>>>(
      w2p, 6144, h1p, 0, 3072, y, y2b, nullptr, b2, nullptr, nullptr, xm);

  // LN2 -> out (sums the two conv2 partials)
  k_ln<<<dim3(8, 16), blk, 0, stream>>>(X2, y, y2b, nullptr, g2, be2, out);
}

// Round 4
// 383.496 us; speedup vs baseline: 1.6396x; 1.6396x over previous
//
#include <hip/hip_runtime.h>

typedef unsigned short u16;
typedef __attribute__((ext_vector_type(4))) float floatx4;
typedef __attribute__((ext_vector_type(8))) __bf16 bf16x8;
typedef __attribute__((ext_vector_type(4))) unsigned short ushort4v;
typedef __attribute__((ext_vector_type(8))) unsigned short ushort8v;

#define DI __device__ __forceinline__

// ---- problem constants ----
// B=8, C=512, T=1024, H=8, F=2048, KS=3, head dim 64, ROPE_D=32, EPS=1e-4

DI u16 f2bf(float f) {
  union { float f; unsigned u; } v; v.f = f;
  unsigned r = v.u + 0x7fffu + ((v.u >> 16) & 1u);
  return (u16)(r >> 16);
}
DI float bf2f(u16 h) {
  union { unsigned u; float f; } v; v.u = ((unsigned)h) << 16;
  return v.f;
}

#define GLDS(g, l) __builtin_amdgcn_global_load_lds( \
    (const __attribute__((address_space(1))) unsigned int*)(g), \
    (__attribute__((address_space(3))) unsigned int*)(l), 16, 0, 0)

// ---------------------------------------------------------------------------
// Batched bf16 MFMA GEMM (z = batch*head), gemm_bt form, BK=64 (2 half-tiles).
// MODE 1 = scores (scale + bit-mask, bf16 out), MODE 2 = PV (write o^T (B,T,C))
// ---------------------------------------------------------------------------
template<int MODE, int BN>
__global__ __launch_bounds__(256) void k_gemm(
    const u16* __restrict__ A, int lda, long long sAz,
    const u16* __restrict__ Bt, int ldb, long long sBz,
    int K,
    u16* __restrict__ o0,
    const unsigned* __restrict__ mb)
{
  constexpr int BM = 128;
  constexpr int FN = BN / 32;
  __shared__ __align__(16) u16 As[2 * BM * 32];
  __shared__ __align__(16) u16 Bs[2 * BN * 32];

  const int tid  = threadIdx.x;
  const int wave = tid >> 6, lane = tid & 63;
  const int wm = wave >> 1, wn = wave & 1;
  const int lr = lane & 15, kg = lane >> 4;
  const int m0 = blockIdx.x * BM, n0 = blockIdx.y * BN;
  const int z  = blockIdx.z;
  const u16* Ab = A  + (size_t)z * sAz;
  const u16* Bb = Bt + (size_t)z * sBz;

  floatx4 acc[4][FN];
#pragma unroll
  for (int i = 0; i < 4; ++i)
#pragma unroll
    for (int j = 0; j < FN; ++j) acc[i][j] = (floatx4){0.f, 0.f, 0.f, 0.f};

  for (int k0 = 0; k0 < K; k0 += 64) {
#pragma unroll
    for (int h = 0; h < 2; ++h) {
#pragma unroll
      for (int ch = 0; ch < BM / 64; ++ch) {
        int idx = ch * 256 + tid;
        int row = idx >> 2, kk = (idx & 3) << 3;
        GLDS(Ab + (size_t)(m0 + row) * lda + (k0 + h * 32 + kk),
             &As[h * BM * 32 + idx * 8]);
      }
#pragma unroll
      for (int ch = 0; ch < BN / 64; ++ch) {
        int idx = ch * 256 + tid;
        int row = idx >> 2, kk = (idx & 3) << 3;
        GLDS(Bb + (size_t)(n0 + row) * ldb + (k0 + h * 32 + kk),
             &Bs[h * BN * 32 + idx * 8]);
      }
    }
    __syncthreads();
    bf16x8 af[2][4], bfr[2][FN];
#pragma unroll
    for (int h = 0; h < 2; ++h) {
#pragma unroll
      for (int i = 0; i < 4; ++i)
        af[h][i] = *(const bf16x8*)&As[(h * BM + wm * 64 + i * 16 + lr) * 32 + kg * 8];
#pragma unroll
      for (int j = 0; j < FN; ++j)
        bfr[h][j] = *(const bf16x8*)&Bs[(h * BN + wn * (BN / 2) + j * 16 + lr) * 32 + kg * 8];
    }
#pragma unroll
    for (int h = 0; h < 2; ++h)
#pragma unroll
      for (int i = 0; i < 4; ++i)
#pragma unroll
        for (int j = 0; j < FN; ++j)
          acc[i][j] = __builtin_amdgcn_mfma_f32_16x16x32_bf16(af[h][i], bfr[h][j], acc[i][j], 0, 0, 0);
    __syncthreads();
  }

  const int wrow0 = m0 + wm * 64;
  const int col0  = n0 + wn * (BN / 2);

  if constexpr (MODE == 1) {  // ---- scores: *1/8, bit-mask, bf16 ----
    const int bb = z >> 3;
#pragma unroll
    for (int i = 0; i < 4; ++i)
#pragma unroll
      for (int j = 0; j < FN; ++j) {
        const int cc = col0 + j * 16 + lr;
#pragma unroll
        for (int r = 0; r < 4; ++r) {
          const int rr = wrow0 + i * 16 + kg * 4 + r;
          float sv = acc[i][j][r] * 0.125f;
          const unsigned mw = mb[((size_t)bb << 15) + ((size_t)rr << 5) + (cc >> 5)];
          if (!((mw >> (cc & 31)) & 1u)) sv = -10000.f;
          o0[((size_t)z * 1024 + rr) * 1024 + cc] = f2bf(sv);
        }
      }
  } else {                    // ---- PV: write o^T (B,T,C) ----
    const int bb = z >> 3, hh = z & 7;
#pragma unroll
    for (int i = 0; i < 4; ++i)
#pragma unroll
      for (int j = 0; j < FN; ++j) {
        const int dk = col0 + j * 16 + lr;
#pragma unroll
        for (int r = 0; r < 4; ++r) {
          const int t = wrow0 + i * 16 + kg * 4 + r;
          o0[((size_t)bb * 1024 + t) * 512 + hh * 64 + dk] = f2bf(acc[i][j][r]);
        }
      }
  }
}

// ---------------------------------------------------------------------------
// Flat GEMM (batch folded into N=8192), gemm_bt form, XCD-swizzled, BK=64.
// A (M x Ktot) row-major, lda = row stride. K = this block's K-slice length;
// koff = blockIdx.z * K (split-K via grid z, MODE 5 only).
//   TAPK == 0 : Bt row bt, row stride ldb
//   TAPK > 0  : conv tap mode — B[bt, k] = Bpad[b, t + k/TAPK, k%TAPK],
//               Bpad (B, 1026, TAPK) zero-padded rows 0 / 1025.
// MODE 0=QKV(+bias+rope+scatter) 3=oproj(+bias -> y1T (B,T,C))
// MODE 4=conv1(relu*mask -> padded h1) 5=conv2(split-K partials -> (B,T,C))
// ---------------------------------------------------------------------------
template<int MODE, int BN, int TAPK>
__global__ __launch_bounds__(256) void k_cgemm(
    const u16* __restrict__ A, int lda,
    const u16* __restrict__ Bsrc, int ldb,
    int K,
    u16* __restrict__ o0, u16* __restrict__ o1, u16* __restrict__ o2,
    const float* __restrict__ bias,
    const float* __restrict__ ctab, const float* __restrict__ stab,
    const float* __restrict__ msk)
{
  constexpr int BM = 128;
  constexpr int FN = BN / 32;
  __shared__ __align__(16) u16 As[2 * BM * 32];
  __shared__ __align__(16) u16 Bs[2 * BN * 32];

  const int tid  = threadIdx.x;
  const int wave = tid >> 6, lane = tid & 63;
  const int wm = wave >> 1, wn = wave & 1;
  const int lr = lane & 15, kg = lane >> 4;

  // XCD-aware bijective swizzle (nwg % 8 == 0 for all our grids)
  const int nwg = gridDim.x * gridDim.y;
  const int h0  = blockIdx.y * gridDim.x + blockIdx.x;
  const int cpx = nwg >> 3;
  const int tl  = (h0 & 7) * cpx + (h0 >> 3);
  const int bx  = tl % gridDim.x;
  const int by  = tl / gridDim.x;

  const int m0 = bx * BM, n0 = by * BN;
  const int koff = blockIdx.z * K;

  floatx4 acc[4][FN];
#pragma unroll
  for (int i = 0; i < 4; ++i)
#pragma unroll
    for (int j = 0; j < FN; ++j) acc[i][j] = (floatx4){0.f, 0.f, 0.f, 0.f};

  for (int k0 = 0; k0 < K; k0 += 64) {
#pragma unroll
    for (int h = 0; h < 2; ++h) {
      const int kglob = koff + k0 + h * 32;
#pragma unroll
      for (int ch = 0; ch < BM / 64; ++ch) {
        int idx = ch * 256 + tid;
        int row = idx >> 2, kk = (idx & 3) << 3;
        GLDS(A + (size_t)(m0 + row) * lda + (kglob + kk),
             &As[h * BM * 32 + idx * 8]);
      }
#pragma unroll
      for (int ch = 0; ch < BN / 64; ++ch) {
        int idx = ch * 256 + tid;
        int row = idx >> 2, kk = (idx & 3) << 3;
        const int bt = n0 + row;
        const u16* src;
        if constexpr (TAPK == 0) {
          src = Bsrc + (size_t)bt * ldb + (kglob + kk);
        } else {
          const int tap = kglob / TAPK, off2 = kglob - tap * TAPK;
          const int b = bt >> 10, t = bt & 1023;
          src = Bsrc + ((size_t)(b * 1026 + t + tap)) * TAPK + off2 + kk;
        }
        GLDS(src, &Bs[h * BN * 32 + idx * 8]);
      }
    }
    __syncthreads();
    bf16x8 af[2][4], bfr[2][FN];
#pragma unroll
    for (int h = 0; h < 2; ++h) {
#pragma unroll
      for (int i = 0; i < 4; ++i)
        af[h][i] = *(const bf16x8*)&As[(h * BM + wm * 64 + i * 16 + lr) * 32 + kg * 8];
#pragma unroll
      for (int j = 0; j < FN; ++j)
        bfr[h][j] = *(const bf16x8*)&Bs[(h * BN + wn * (BN / 2) + j * 16 + lr) * 32 + kg * 8];
    }
#pragma unroll
    for (int h = 0; h < 2; ++h)
#pragma unroll
      for (int i = 0; i < 4; ++i)
#pragma unroll
        for (int j = 0; j < FN; ++j)
          acc[i][j] = __builtin_amdgcn_mfma_f32_16x16x32_bf16(af[h][i], bfr[h][j], acc[i][j], 0, 0, 0);
    __syncthreads();
  }

  const int wrow0 = m0 + wm * 64;
  const int col0  = n0 + wn * (BN / 2);

  if constexpr (MODE == 0) {  // ---- QKV: bias + RoPE + scatter ----
    float v[4][FN][4];
#pragma unroll
    for (int i = 0; i < 4; ++i)
#pragma unroll
      for (int j = 0; j < FN; ++j)
#pragma unroll
        for (int r = 0; r < 4; ++r)
          v[i][j][r] = acc[i][j][r] + bias[wrow0 + i * 16 + kg * 4 + r];
    const int sec = wrow0 >> 9;            // 0=q 1=k 2=v
    const int hh  = (wrow0 & 511) >> 6;    // head
    if (sec < 2) {
#pragma unroll
      for (int j = 0; j < FN; ++j) {
        const int t = (col0 + j * 16 + lr) & 1023;
#pragma unroll
        for (int r = 0; r < 4; ++r) {
          const int a = kg * 4 + r;
          const float cv = ctab[t * 16 + a], sv = stab[t * 16 + a];
          const float a0 = v[0][j][r], a1 = v[1][j][r];
          v[0][j][r] = a0 * cv - a1 * sv;
          v[1][j][r] = a1 * cv + a0 * sv;
        }
      }
      u16* dst = (sec == 0) ? o0 : o1;     // q,k: (B,H,T,64)
#pragma unroll
      for (int i = 0; i < 4; ++i)
#pragma unroll
        for (int j = 0; j < FN; ++j) {
          const int bt = col0 + j * 16 + lr;
          const int b = bt >> 10, t = bt & 1023;
          ushort4v pk;
#pragma unroll
          for (int r = 0; r < 4; ++r) pk[r] = f2bf(v[i][j][r]);
          *(ushort4v*)&dst[(((size_t)b * 8 + hh) * 1024 + t) * 64 + i * 16 + kg * 4] = pk;
        }
    } else {                               // v: (B,H,64,T)
#pragma unroll
      for (int i = 0; i < 4; ++i)
#pragma unroll
        for (int j = 0; j < FN; ++j) {
          const int bt = col0 + j * 16 + lr;
          const int b = bt >> 10, t = bt & 1023;
#pragma unroll
          for (int r = 0; r < 4; ++r) {
            const int dk = i * 16 + kg * 4 + r;
            o2[(((size_t)b * 8 + hh) * 64 + dk) * 1024 + t] = f2bf(v[i][j][r]);
          }
        }
    }
  } else if constexpr (MODE == 3) {  // ---- O-proj: +bias -> y1T (B,T,C) ----
#pragma unroll
    for (int i = 0; i < 4; ++i)
#pragma unroll
      for (int j = 0; j < FN; ++j) {
        const int bt = col0 + j * 16 + lr;
        const int c0 = wrow0 + i * 16 + kg * 4;
        ushort4v pk;
#pragma unroll
        for (int r = 0; r < 4; ++r) pk[r] = f2bf(acc[i][j][r] + bias[c0 + r]);
        *(ushort4v*)&o0[(size_t)bt * 512 + c0] = pk;
      }
  } else if constexpr (MODE == 4) {  // ---- conv1: relu(acc+b1)*mask -> h1pad ----
#pragma unroll
    for (int i = 0; i < 4; ++i) {
      const int r0 = wrow0 + i * 16 + kg * 4;
#pragma unroll
      for (int j = 0; j < FN; ++j) {
        const int bt = col0 + j * 16 + lr;
        const int b = bt >> 10, t = bt & 1023;
        const float mv = msk[(size_t)b * 1024 + t];
        ushort4v pk;
#pragma unroll
        for (int r = 0; r < 4; ++r)
          pk[r] = f2bf(fmaxf(acc[i][j][r] + bias[r0 + r], 0.f) * mv);
        *(ushort4v*)&o0[((size_t)(b * 1026 + t + 1)) * 2048 + r0] = pk;
      }
    }
  } else {                           // ---- conv2 split-K partial -> (B,T,C) ----
    u16* dst = (blockIdx.z == 0) ? o0 : o1;
#pragma unroll
    for (int i = 0; i < 4; ++i)
#pragma unroll
      for (int j = 0; j < FN; ++j) {
        const int bt = col0 + j * 16 + lr;
        const int b = bt >> 10, t = bt & 1023;
        const int c0 = wrow0 + i * 16 + kg * 4;
        const float mv = msk[(size_t)b * 1024 + t];
        ushort4v pk;
#pragma unroll
        for (int r = 0; r < 4; ++r) {
          const float bv = (blockIdx.z == 0) ? bias[c0 + r] : 0.f;
          pk[r] = f2bf((acc[i][j][r] + bv) * mv);
        }
        *(ushort4v*)&dst[(size_t)bt * 512 + c0] = pk;
      }
  }
}

// ---------------------------------------------------------------------------
// glue kernels
// ---------------------------------------------------------------------------
__global__ __launch_bounds__(256) void k_cvt(const float* __restrict__ in, u16* __restrict__ out, int n) {
  int i = blockIdx.x * 256 + threadIdx.x;
  if (i < n) out[i] = f2bf(in[i]);
}

__global__ __launch_bounds__(256) void k_repack_w1(const float* __restrict__ in, u16* __restrict__ out) {
  int i = blockIdx.x * 256 + threadIdx.x;          // over 2048*1536
  int f = i / 1536, rem = i % 1536;
  int kk = rem >> 9, c = rem & 511;                // out (F, KS, C)
  out[i] = f2bf(in[f * 1536 + c * 3 + kk]);
}

__global__ __launch_bounds__(256) void k_repack_w2(const float* __restrict__ in, u16* __restrict__ out) {
  int i = blockIdx.x * 256 + threadIdx.x;          // over 512*6144
  int c = i / 6144, rem = i % 6144;
  int kk = rem >> 11, f = rem & 2047;              // out (C, KS, F)
  out[i] = f2bf(in[c * 6144 + f * 3 + kk]);
}

__global__ __launch_bounds__(256) void k_bias_concat(const float* __restrict__ bq, const float* __restrict__ bk,
                                                     const float* __restrict__ bv, float* __restrict__ out) {
  int i = blockIdx.x * 256 + threadIdx.x;
  if (i < 512) out[i] = bq[i];
  else if (i < 1024) out[i] = bk[i - 512];
  else if (i < 1536) out[i] = bv[i - 1024];
}

__global__ __launch_bounds__(256) void k_rope_tables(float* __restrict__ ct, float* __restrict__ st) {
  int i = blockIdx.x * 256 + threadIdx.x;          // 1024*16
  int t = i >> 4, a = i & 15;
  float theta = powf(10000.f, -(float)a / 16.f);
  float ang = (float)t * theta;
  ct[i] = cosf(ang);
  st[i] = sinf(ang);
}

// pack attn_mask (B,1,T,T) fp32 -> bits; word i covers cols [i*32, i*32+32)
__global__ __launch_bounds__(256) void k_maskpack(const float* __restrict__ am, unsigned* __restrict__ mb) {
  int i = blockIdx.x * 256 + threadIdx.x;          // 8*1024*32 words
  const float* src = am + (size_t)i * 32;
  unsigned w = 0;
#pragma unroll
  for (int q = 0; q < 32; ++q) w |= (src[q] != 0.f) ? (1u << q) : 0u;
  mb[i] = w;
}

// zero pad rows (row 0 and 1025 of each batch) of a (B,1026,R) bf16 buffer
__global__ __launch_bounds__(256) void k_zrows(u16* __restrict__ p, int R) {
  const int b = blockIdx.x >> 1;
  const size_t row = (blockIdx.x & 1) ? 1025 : 0;
  u16* r = p + ((size_t)b * 1026 + row) * R;
  for (int i = threadIdx.x; i < R; i += 256) r[i] = 0;
}

// tiled fp32 (B,R,TT) -> bf16 (B,TT,R) transpose-convert, column mask applied
__global__ __launch_bounds__(256) void k_tcvt(const float* __restrict__ in, u16* __restrict__ out,
                                              const float* __restrict__ msk, int R, int TT) {
  __shared__ u16 tile[64][65];
  const int b = blockIdx.z;
  const int r0 = blockIdx.x * 64, t0 = blockIdx.y * 64;
  const int tx = threadIdx.x & 63, ty = threadIdx.x >> 6;
  const float mv = msk ? msk[(size_t)b * TT + t0 + tx] : 1.f;
  const float* ib = in + (size_t)b * R * TT;
#pragma unroll
  for (int rr = ty; rr < 64; rr += 4)
    tile[rr][tx] = f2bf(ib[(size_t)(r0 + rr) * TT + t0 + tx] * mv);
  __syncthreads();
  u16* ob = out + (size_t)b * TT * R;
#pragma unroll
  for (int tt = ty; tt < 64; tt += 4)
    ob[(size_t)(t0 + tt) * R + r0 + tx] = tile[tx][tt];
}

// in-place softmax, one WAVE per row of 1024 (no LDS, no barriers)
__global__ __launch_bounds__(256) void k_softmax(u16* __restrict__ s) {
  const int lane = threadIdx.x & 63, wv = threadIdx.x >> 6;
  const size_t row = (size_t)blockIdx.x * 4 + wv;
  u16* p = s + row * 1024;
  ushort8v ua = *(const ushort8v*)&p[lane * 8];
  ushort8v ub = *(const ushort8v*)&p[512 + lane * 8];
  float va[8], vb[8];
  float mx = -3.4e38f;
#pragma unroll
  for (int q = 0; q < 8; ++q) {
    va[q] = bf2f(ua[q]); vb[q] = bf2f(ub[q]);
    mx = fmaxf(mx, fmaxf(va[q], vb[q]));
  }
#pragma unroll
  for (int o = 32; o; o >>= 1) mx = fmaxf(mx, __shfl_xor(mx, o));
  const float L2E = 1.44269504f;
  float sm = 0.f;
#pragma unroll
  for (int q = 0; q < 8; ++q) {
    va[q] = exp2f((va[q] - mx) * L2E);
    vb[q] = exp2f((vb[q] - mx) * L2E);
    sm += va[q] + vb[q];
  }
#pragma unroll
  for (int o = 32; o; o >>= 1) sm += __shfl_xor(sm, o);
  const float inv = 1.f / sm;
  ushort8v oa, ob;
#pragma unroll
  for (int q = 0; q < 8; ++q) { oa[q] = f2bf(va[q] * inv); ob[q] = f2bf(vb[q] * inv); }
  *(ushort8v*)&p[lane * 8] = oa;
  *(ushort8v*)&p[512 + lane * 8] = ob;
}

// LN1: one wave per (b,t) row of 512. r = xbT + y1T (both (B,T,C) bf16).
// Writes x2T (B,T,C) bf16 (LN out, residual for LN2) and x2p (B,1026,C) masked.
__global__ __launch_bounds__(256) void k_ln1(
    const u16* __restrict__ xbT, const u16* __restrict__ y1T,
    const float* __restrict__ xm, const float* __restrict__ g,
    const float* __restrict__ be, u16* __restrict__ x2T, u16* __restrict__ x2p)
{
  const int lane = threadIdx.x & 63, wv = threadIdx.x >> 6;
  const int row = blockIdx.x * 4 + wv;          // b*1024 + t
  const int b = row >> 10, t = row & 1023;
  const size_t base = (size_t)row * 512 + lane * 8;
  ushort8v ux = *(const ushort8v*)&xbT[base];
  ushort8v uy = *(const ushort8v*)&y1T[base];
  float v[8];
  float sum = 0.f, ss = 0.f;
#pragma unroll
  for (int q = 0; q < 8; ++q) {
    v[q] = bf2f(ux[q]) + bf2f(uy[q]);
    sum += v[q]; ss += v[q] * v[q];
  }
#pragma unroll
  for (int o = 32; o; o >>= 1) { sum += __shfl_xor(sum, o); ss += __shfl_xor(ss, o); }
  const float mean = sum * (1.f / 512.f);
  const float var  = ss * (1.f / 512.f) - mean * mean;
  const float rs   = rsqrtf(var + 1e-4f);
  const float m    = xm[(size_t)b * 1024 + t];
  ushort8v on, om;
#pragma unroll
  for (int q = 0; q < 8; ++q) {
    const int c = lane * 8 + q;
    const float nv = (v[q] - mean) * rs * g[c] + be[c];
    on[q] = f2bf(nv);
    om[q] = f2bf(nv * m);
  }
  *(ushort8v*)&x2T[base] = on;
  *(ushort8v*)&x2p[((size_t)(b * 1026 + t + 1)) * 512 + lane * 8] = om;
}

// LN2 stats: one wave per row; r = x2T + y2aT + y2bT; write (mean, rstd)
__global__ __launch_bounds__(256) void k_ln2_stats(
    const u16* __restrict__ x2T, const u16* __restrict__ y2a,
    const u16* __restrict__ y2b, float2* __restrict__ mr)
{
  const int lane = threadIdx.x & 63, wv = threadIdx.x >> 6;
  const int row = blockIdx.x * 4 + wv;
  const size_t base = (size_t)row * 512 + lane * 8;
  ushort8v u0 = *(const ushort8v*)&x2T[base];
  ushort8v u1 = *(const ushort8v*)&y2a[base];
  ushort8v u2 = *(const ushort8v*)&y2b[base];
  float sum = 0.f, ss = 0.f;
#pragma unroll
  for (int q = 0; q < 8; ++q) {
    const float v = bf2f(u0[q]) + bf2f(u1[q]) + bf2f(u2[q]);
    sum += v; ss += v * v;
  }
#pragma unroll
  for (int o = 32; o; o >>= 1) { sum += __shfl_xor(sum, o); ss += __shfl_xor(ss, o); }
  if (lane == 0) {
    const float mean = sum * (1.f / 512.f);
    const float var  = ss * (1.f / 512.f) - mean * mean;
    mr[row] = (float2){mean, rsqrtf(var + 1e-4f)};
  }
}

// LN2 write: normalize + transpose to out (B,C,T) fp32.
// block = (c-chunk 64, t-tile 64, b); 256 threads.
__global__ __launch_bounds__(256) void k_ln2_write(
    const u16* __restrict__ x2T, const u16* __restrict__ y2a,
    const u16* __restrict__ y2b, const float2* __restrict__ mr,
    const float* __restrict__ g, const float* __restrict__ be,
    float* __restrict__ out)
{
  __shared__ float tile[64][65];
  const int cc0 = blockIdx.x * 64, t0 = blockIdx.y * 64, b = blockIdx.z;
  const int tid = threadIdx.x;
  // phase 1: read rows (coalesced along c), normalize, store to LDS
  const int c4 = (tid & 15) * 4;          // 0..60
  const int tr = tid >> 4;                // 0..15
  float g4[4], b4[4];
#pragma unroll
  for (int q = 0; q < 4; ++q) { g4[q] = g[cc0 + c4 + q]; b4[q] = be[cc0 + c4 + q]; }
#pragma unroll
  for (int it = 0; it < 4; ++it) {
    const int tt = tr + it * 16;
    const int row = b * 1024 + t0 + tt;
    const size_t base = (size_t)row * 512 + cc0 + c4;
    ushort4v u0 = *(const ushort4v*)&x2T[base];
    ushort4v u1 = *(const ushort4v*)&y2a[base];
    ushort4v u2 = *(const ushort4v*)&y2b[base];
    const float2 s = mr[row];
#pragma unroll
    for (int q = 0; q < 4; ++q) {
      const float v = bf2f(u0[q]) + bf2f(u1[q]) + bf2f(u2[q]);
      tile[tt][c4 + q] = (v - s.x) * s.y * g4[q] + b4[q];
    }
  }
  __syncthreads();
  // phase 2: write out (B,C,T) coalesced along t
  const int tx = tid & 63, cg = tid >> 6;
#pragma unroll
  for (int c = cg; c < 64; c += 4)
    out[((size_t)b * 512 + cc0 + c) * 1024 + t0 + tx] = tile[tx][c];
}

// ---------------------------------------------------------------------------
extern "C" void kernel_launch(void* const* d_in, const int* in_sizes, int n_in,
                              void* d_out, int out_size, void* d_ws, size_t ws_size,
                              hipStream_t stream) {
  (void)in_sizes; (void)n_in; (void)out_size; (void)ws_size;
  const float* x   = (const float*)d_in[0];
  const float* xm  = (const float*)d_in[1];
  const float* am  = (const float*)d_in[2];
  const float* wq  = (const float*)d_in[3];
  const float* bq  = (const float*)d_in[4];
  const float* wk  = (const float*)d_in[5];
  const float* bk  = (const float*)d_in[6];
  const float* wv  = (const float*)d_in[7];
  const float* bv  = (const float*)d_in[8];
  const float* wo  = (const float*)d_in[9];
  const float* bo  = (const float*)d_in[10];
  const float* w1  = (const float*)d_in[11];
  const float* b1  = (const float*)d_in[12];
  const float* w2  = (const float*)d_in[13];
  const float* b2  = (const float*)d_in[14];
  const float* g1  = (const float*)d_in[15];
  const float* be1 = (const float*)d_in[16];
  const float* g2  = (const float*)d_in[17];
  const float* be2 = (const float*)d_in[18];
  float* out = (float*)d_out;

  char* ws = (char*)d_ws;
  size_t off = 0;
  auto alloc = [&](size_t bytes) { char* p = ws + off; off += (bytes + 255) & ~(size_t)255; return p; };

  u16*   wqkv = (u16*)  alloc((size_t)1536 * 512 * 2);
  u16*   wob  = (u16*)  alloc((size_t)512 * 512 * 2);
  u16*   w1p  = (u16*)  alloc((size_t)2048 * 1536 * 2);
  u16*   w2p  = (u16*)  alloc((size_t)512 * 6144 * 2);
  float* bqkv = (float*)alloc(1536 * 4);
  float* ctab = (float*)alloc(1024 * 16 * 4);
  float* stab = (float*)alloc(1024 * 16 * 4);
  unsigned* mbits = (unsigned*)alloc((size_t)8 * 1024 * 32 * 4);
  float2* mr  = (float2*)alloc((size_t)8192 * 8);
  u16*   x2T  = (u16*)  alloc((size_t)8 * 1024 * 512 * 2);   // LN1 out (B,T,C)
  u16*   x2p  = (u16*)  alloc((size_t)8 * 1026 * 512 * 2);   // LN1 out masked, padded
  u16*   h1p  = (u16*)  alloc((size_t)8 * 1026 * 2048 * 2);  // conv1 out, padded (B,1026,F)
  u16*   y1T  = (u16*)  alloc((size_t)8 * 1024 * 512 * 2);   // attn out; conv2 partial A
  u16*   xbT  = (u16*)  alloc((size_t)8 * 1024 * 512 * 2);   // masked x^T (B,T,C)
  u16*   oT   = (u16*)  alloc((size_t)8 * 1024 * 512 * 2);   // PV out; conv2 partial B
  u16*   qkv3 = (u16*)  alloc((size_t)3 * 8 * 8 * 1024 * 64 * 2); // q,k,v
  u16*   sb   = (u16*)  alloc((size_t)8 * 8 * 1024 * 1024 * 2);   // scores / p

  u16* qb   = qkv3;
  u16* kb   = qkv3 + (size_t)8 * 8 * 1024 * 64;
  u16* vb   = kb   + (size_t)8 * 8 * 1024 * 64;
  u16* y2aT = y1T;   // conv2 partial A reuses y1T (dead after LN1)
  u16* y2bT = oT;    // conv2 partial B reuses oT  (dead after O-proj)

  dim3 blk(256);

  // weight/bias/table prep
  k_cvt<<<dim3(1024), blk, 0, stream>>>(wq, wqkv, 512 * 512);
  k_cvt<<<dim3(1024), blk, 0, stream>>>(wk, wqkv + 512 * 512, 512 * 512);
  k_cvt<<<dim3(1024), blk, 0, stream>>>(wv, wqkv + 2 * 512 * 512, 512 * 512);
  k_cvt<<<dim3(1024), blk, 0, stream>>>(wo, wob, 512 * 512);
  k_repack_w1<<<dim3(12288), blk, 0, stream>>>(w1, w1p);
  k_repack_w2<<<dim3(12288), blk, 0, stream>>>(w2, w2p);
  k_bias_concat<<<dim3(6), blk, 0, stream>>>(bq, bk, bv, bqkv);
  k_rope_tables<<<dim3(64), blk, 0, stream>>>(ctab, stab);
  k_maskpack<<<dim3(1024), blk, 0, stream>>>(am, mbits);
  k_zrows<<<dim3(16), blk, 0, stream>>>(x2p, 512);
  k_zrows<<<dim3(16), blk, 0, stream>>>(h1p, 2048);

  // x^T (masked, bf16)
  k_tcvt<<<dim3(8, 16, 8), blk, 0, stream>>>(x, xbT, xm, 512, 1024);

  // QKV projection + bias + rope + head scatter  (flat N=8192)
  k_cgemm<0, 128, 0><<<dim3(12, 64), blk, 0, stream>>>(
      wqkv, 512, xbT, 512, 512, qb, kb, vb, bqkv, ctab, stab, nullptr);

  // scores = q k^T / 8 (+ bit-mask), bf16
  k_gemm<1, 128><<<dim3(8, 8, 64), blk, 0, stream>>>(
      qb, 64, 65536, kb, 64, 65536, 64, sb, mbits);

  // softmax rows in place (wave per row)
  k_softmax<<<dim3(16384), blk, 0, stream>>>(sb);

  // o = p v, written as o^T (B,T,C)
  k_gemm<2, 64><<<dim3(8, 1, 64), blk, 0, stream>>>(
      sb, 1024, 1048576, vb, 1024, 65536, 1024, oT, nullptr);

  // y1 = wo o + bo -> y1T (B,T,C)
  k_cgemm<3, 64, 0><<<dim3(4, 128), blk, 0, stream>>>(
      wob, 512, oT, 512, 512, y1T, nullptr, nullptr, bo, nullptr, nullptr, nullptr);

  // LN1 rows -> x2T (residual) + x2p (masked, padded conv input)
  k_ln1<<<dim3(2048), blk, 0, stream>>>(xbT, y1T, xm, g1, be1, x2T, x2p);

  // conv path (tap-shifted padded activations)
  k_cgemm<4, 128, 512><<<dim3(16, 64), blk, 0, stream>>>(
      w1p, 1536, x2p, 0, 1536, h1p, nullptr, nullptr, b1, nullptr, nullptr, xm);
  // conv2: split-K x2 (K-slice 3072 each), T-major partials
  k_cgemm<5, 64, 2048><<<dim3(4, 128, 2), blk, 0, stream>>>(
      w2p, 6144, h1p, 0, 3072, y2aT, y2bT, nullptr, b2, nullptr, nullptr, xm);

  // LN2: stats then transpose-normalize -> out (B,C,T) fp32
  k_ln2_stats<<<dim3(2048), blk, 0, stream>>>(x2T, y2aT, y2bT, mr);
  k_ln2_write<<<dim3(8, 16, 8), blk, 0, stream>>>(x2T, y2aT, y2bT, mr, g2, be2, out);
}

// Round 5
// 332.323 us; speedup vs baseline: 1.8921x; 1.1540x over previous
//
#include <hip/hip_runtime.h>

typedef unsigned short u16;
typedef __attribute__((ext_vector_type(4))) float floatx4;
typedef __attribute__((ext_vector_type(8))) __bf16 bf16x8;
typedef __attribute__((ext_vector_type(4))) unsigned short ushort4v;
typedef __attribute__((ext_vector_type(8))) unsigned short ushort8v;

#define DI __device__ __forceinline__

// ---- problem constants ----
// B=8, C=512, T=1024, H=8, F=2048, KS=3, head dim 64, ROPE_D=32, EPS=1e-4

DI u16 f2bf(float f) {
  union { float f; unsigned u; } v; v.f = f;
  unsigned r = v.u + 0x7fffu + ((v.u >> 16) & 1u);
  return (u16)(r >> 16);
}
DI float bf2f(u16 h) {
  union { unsigned u; float f; } v; v.u = ((unsigned)h) << 16;
  return v.f;
}

#define GLDS(g, l) __builtin_amdgcn_global_load_lds( \
    (const __attribute__((address_space(1))) unsigned int*)(g), \
    (__attribute__((address_space(3))) unsigned int*)(l), 16, 0, 0)

// ---------------------------------------------------------------------------
// Flash attention. grid (8 q-tiles, 64 bh), 256 thr = 4 waves x 32 q-rows.
// q,k (B,H,T,64) roped bf16; v (B,H,64,T) bf16 (= V^T). out oT (B,T,C) bf16.
// Swapped QK^T: sT = mfma(K,Q) -> lane&15 = q-col, so row-softmax is in-lane
// over 16 vals + shfl_xor(16,32). P round-trips through per-wave swizzled LDS
// to become the PV A-operand. K/V/Q frags read direct from global (L2-fit).
// ---------------------------------------------------------------------------
__global__ __launch_bounds__(256) void k_fattn(
    const u16* __restrict__ qb, const u16* __restrict__ kb,
    const u16* __restrict__ vb, const unsigned* __restrict__ mb,
    u16* __restrict__ oT)
{
  __shared__ __align__(16) u16 Ps[4][32 * 64];
  const int tid  = threadIdx.x;
  const int wave = tid >> 6, lane = tid & 63;
  const int lr = lane & 15, kg = lane >> 4;
  const int qt = blockIdx.x, bh = blockIdx.y;
  const int bb = bh >> 3, hh = bh & 7;
  const int wq0 = qt * 128 + wave * 32;
  const float L2E = 1.44269504f;

  const u16* Qp = qb + (size_t)bh * 65536;
  const u16* Kp = kb + (size_t)bh * 65536;
  const u16* Vp = vb + (size_t)bh * 65536;
  u16* Pw = &Ps[wave][0];

  bf16x8 qf[2][2];
#pragma unroll
  for (int i = 0; i < 2; ++i)
#pragma unroll
    for (int h = 0; h < 2; ++h)
      qf[i][h] = *(const bf16x8*)&Qp[(wq0 + i * 16 + lr) * 64 + h * 32 + kg * 8];

  float m_b[2] = {-3.0e38f, -3.0e38f};
  float l_b[2] = {0.f, 0.f};
  floatx4 o_acc[2][4];
#pragma unroll
  for (int i = 0; i < 2; ++i)
#pragma unroll
    for (int j = 0; j < 4; ++j) o_acc[i][j] = (floatx4){0.f, 0.f, 0.f, 0.f};

  for (int s0 = 0; s0 < 1024; s0 += 64) {
    // ---- QK^T (swapped): sT[a][b] row = s (kg*4+r), col = q (lr) ----
    floatx4 sT[4][2];
#pragma unroll
    for (int a = 0; a < 4; ++a) {
      bf16x8 kf[2];
#pragma unroll
      for (int h = 0; h < 2; ++h)
        kf[h] = *(const bf16x8*)&Kp[(s0 + a * 16 + lr) * 64 + h * 32 + kg * 8];
      sT[a][0] = (floatx4){0.f, 0.f, 0.f, 0.f};
      sT[a][1] = (floatx4){0.f, 0.f, 0.f, 0.f};
#pragma unroll
      for (int b = 0; b < 2; ++b)
#pragma unroll
        for (int h = 0; h < 2; ++h)
          sT[a][b] = __builtin_amdgcn_mfma_f32_16x16x32_bf16(kf[h], qf[b][h], sT[a][b], 0, 0, 0);
    }
    // ---- online softmax per q-frag b (q-row = wq0 + b*16 + lr) ----
    float corr[2];
#pragma unroll
    for (int b = 0; b < 2; ++b) {
      const size_t rw = ((size_t)bb << 15) + ((size_t)(wq0 + b * 16 + lr) << 5) + (s0 >> 5);
      const unsigned w0 = mb[rw], w1 = mb[rw + 1];
      float mx = -3.0e38f;
#pragma unroll
      for (int a = 0; a < 4; ++a)
#pragma unroll
        for (int r = 0; r < 4; ++r) {
          const int sl = a * 16 + kg * 4 + r;
          float sv = sT[a][b][r] * 0.125f;
          const unsigned wsel = (sl & 32) ? w1 : w0;
          if (!((wsel >> (sl & 31)) & 1u)) sv = -10000.f;
          sT[a][b][r] = sv;
          mx = fmaxf(mx, sv);
        }
      mx = fmaxf(mx, __shfl_xor(mx, 16));
      mx = fmaxf(mx, __shfl_xor(mx, 32));
      const float mn = fmaxf(m_b[b], mx);
      corr[b] = exp2f((m_b[b] - mn) * L2E);
      m_b[b] = mn;
      float sum = 0.f;
#pragma unroll
      for (int a = 0; a < 4; ++a)
#pragma unroll
        for (int r = 0; r < 4; ++r) {
          const float p = exp2f((sT[a][b][r] - mn) * L2E);
          sT[a][b][r] = p;
          sum += p;
        }
      sum += __shfl_xor(sum, 16);
      sum += __shfl_xor(sum, 32);
      l_b[b] = l_b[b] * corr[b] + sum;
      // write P rows into per-wave LDS [q][s], XOR-swizzled
#pragma unroll
      for (int a = 0; a < 4; ++a)
#pragma unroll
        for (int r = 0; r < 4; ++r) {
          const int sl = a * 16 + kg * 4 + r;
          __bf16 hv = (__bf16)sT[a][b][r];
          Pw[(b * 16 + lr) * 64 + (sl ^ ((lr & 7) << 3))] = *(u16*)&hv;
        }
    }
    // ---- rescale O by corr (broadcast to (kg*4+r)-row mapping) ----
#pragma unroll
    for (int i = 0; i < 2; ++i)
#pragma unroll
      for (int r = 0; r < 4; ++r) {
        const float cv = __shfl(corr[i], kg * 4 + r);
#pragma unroll
        for (int jd = 0; jd < 4; ++jd) o_acc[i][jd][r] *= cv;
      }
    asm volatile("s_waitcnt lgkmcnt(0)" ::: "memory");
    __builtin_amdgcn_sched_barrier(0);
    // ---- PV: A = P from LDS, B = V^T rows direct from global ----
    bf16x8 pa[2][2];
#pragma unroll
    for (int i = 0; i < 2; ++i)
#pragma unroll
      for (int h = 0; h < 2; ++h)
        pa[i][h] = *(const bf16x8*)&Pw[(i * 16 + lr) * 64 + (((h * 4 + kg) ^ (lr & 7)) << 3)];
#pragma unroll
    for (int jd = 0; jd < 4; ++jd) {
      bf16x8 vf[2];
#pragma unroll
      for (int h = 0; h < 2; ++h)
        vf[h] = *(const bf16x8*)&Vp[(jd * 16 + lr) * 1024 + s0 + h * 32 + kg * 8];
#pragma unroll
      for (int i = 0; i < 2; ++i)
#pragma unroll
        for (int h = 0; h < 2; ++h)
          o_acc[i][jd] = __builtin_amdgcn_mfma_f32_16x16x32_bf16(pa[i][h], vf[h], o_acc[i][jd], 0, 0, 0);
    }
  }
  // ---- epilogue: divide by l, store oT (B,T,C) ----
  float linv[2][4];
#pragma unroll
  for (int i = 0; i < 2; ++i)
#pragma unroll
    for (int r = 0; r < 4; ++r) linv[i][r] = 1.f / __shfl(l_b[i], kg * 4 + r);
#pragma unroll
  for (int i = 0; i < 2; ++i)
#pragma unroll
    for (int jd = 0; jd < 4; ++jd)
#pragma unroll
      for (int r = 0; r < 4; ++r) {
        const int t = wq0 + i * 16 + kg * 4 + r;
        const int c = hh * 64 + jd * 16 + lr;
        oT[((size_t)bb * 1024 + t) * 512 + c] = f2bf(o_acc[i][jd][r] * linv[i][r]);
      }
}

// ---------------------------------------------------------------------------
// Flat GEMM (batch folded into N=8192), gemm_bt form, XCD-swizzled, BK=64.
// A (M x Ktot) row-major, lda = row stride. K = this block's K-slice length;
// koff = blockIdx.z * K (split-K via grid z, MODE 5 only).
//   TAPK == 0 : Bt row bt, row stride ldb
//   TAPK > 0  : conv tap mode — B[bt, k] = Bpad[b, t + k/TAPK, k%TAPK],
//               Bpad (B, 1026, TAPK) zero-padded rows 0 / 1025.
// MODE 0=QKV(+bias+rope+scatter) 3=oproj(+bias -> y1T (B,T,C))
// MODE 4=conv1(relu*mask -> padded h1) 5=conv2(split-K partials -> (B,T,C))
// ---------------------------------------------------------------------------
template<int MODE, int BN, int TAPK>
__global__ __launch_bounds__(256) void k_cgemm(
    const u16* __restrict__ A, int lda,
    const u16* __restrict__ Bsrc, int ldb,
    int K,
    u16* __restrict__ o0, u16* __restrict__ o1, u16* __restrict__ o2,
    const float* __restrict__ bias,
    const float* __restrict__ ctab, const float* __restrict__ stab,
    const float* __restrict__ msk)
{
  constexpr int BM = 128;
  constexpr int FN = BN / 32;
  __shared__ __align__(16) u16 As[2 * BM * 32];
  __shared__ __align__(16) u16 Bs[2 * BN * 32];

  const int tid  = threadIdx.x;
  const int wave = tid >> 6, lane = tid & 63;
  const int wm = wave >> 1, wn = wave & 1;
  const int lr = lane & 15, kg = lane >> 4;

  // XCD-aware bijective swizzle (nwg % 8 == 0 for all our grids)
  const int nwg = gridDim.x * gridDim.y;
  const int h0  = blockIdx.y * gridDim.x + blockIdx.x;
  const int cpx = nwg >> 3;
  const int tl  = (h0 & 7) * cpx + (h0 >> 3);
  const int bx  = tl % gridDim.x;
  const int by  = tl / gridDim.x;

  const int m0 = bx * BM, n0 = by * BN;
  const int koff = blockIdx.z * K;

  floatx4 acc[4][FN];
#pragma unroll
  for (int i = 0; i < 4; ++i)
#pragma unroll
    for (int j = 0; j < FN; ++j) acc[i][j] = (floatx4){0.f, 0.f, 0.f, 0.f};

  for (int k0 = 0; k0 < K; k0 += 64) {
#pragma unroll
    for (int h = 0; h < 2; ++h) {
      const int kglob = koff + k0 + h * 32;
#pragma unroll
      for (int ch = 0; ch < BM / 64; ++ch) {
        int idx = ch * 256 + tid;
        int row = idx >> 2, kk = (idx & 3) << 3;
        GLDS(A + (size_t)(m0 + row) * lda + (kglob + kk),
             &As[h * BM * 32 + idx * 8]);
      }
#pragma unroll
      for (int ch = 0; ch < BN / 64; ++ch) {
        int idx = ch * 256 + tid;
        int row = idx >> 2, kk = (idx & 3) << 3;
        const int bt = n0 + row;
        const u16* src;
        if constexpr (TAPK == 0) {
          src = Bsrc + (size_t)bt * ldb + (kglob + kk);
        } else {
          const int tap = kglob / TAPK, off2 = kglob - tap * TAPK;
          const int b = bt >> 10, t = bt & 1023;
          src = Bsrc + ((size_t)(b * 1026 + t + tap)) * TAPK + off2 + kk;
        }
        GLDS(src, &Bs[h * BN * 32 + idx * 8]);
      }
    }
    __syncthreads();
    bf16x8 af[2][4], bfr[2][FN];
#pragma unroll
    for (int h = 0; h < 2; ++h) {
#pragma unroll
      for (int i = 0; i < 4; ++i)
        af[h][i] = *(const bf16x8*)&As[(h * BM + wm * 64 + i * 16 + lr) * 32 + kg * 8];
#pragma unroll
      for (int j = 0; j < FN; ++j)
        bfr[h][j] = *(const bf16x8*)&Bs[(h * BN + wn * (BN / 2) + j * 16 + lr) * 32 + kg * 8];
    }
#pragma unroll
    for (int h = 0; h < 2; ++h)
#pragma unroll
      for (int i = 0; i < 4; ++i)
#pragma unroll
        for (int j = 0; j < FN; ++j)
          acc[i][j] = __builtin_amdgcn_mfma_f32_16x16x32_bf16(af[h][i], bfr[h][j], acc[i][j], 0, 0, 0);
    __syncthreads();
  }

  const int wrow0 = m0 + wm * 64;
  const int col0  = n0 + wn * (BN / 2);

  if constexpr (MODE == 0) {  // ---- QKV: bias + RoPE + scatter ----
    float v[4][FN][4];
#pragma unroll
    for (int i = 0; i < 4; ++i)
#pragma unroll
      for (int j = 0; j < FN; ++j)
#pragma unroll
        for (int r = 0; r < 4; ++r)
          v[i][j][r] = acc[i][j][r] + bias[wrow0 + i * 16 + kg * 4 + r];
    const int sec = wrow0 >> 9;            // 0=q 1=k 2=v
    const int hh  = (wrow0 & 511) >> 6;    // head
    if (sec < 2) {
#pragma unroll
      for (int j = 0; j < FN; ++j) {
        const int t = (col0 + j * 16 + lr) & 1023;
#pragma unroll
        for (int r = 0; r < 4; ++r) {
          const int a = kg * 4 + r;
          const float cv = ctab[t * 16 + a], sv = stab[t * 16 + a];
          const float a0 = v[0][j][r], a1 = v[1][j][r];
          v[0][j][r] = a0 * cv - a1 * sv;
          v[1][j][r] = a1 * cv + a0 * sv;
        }
      }
      u16* dst = (sec == 0) ? o0 : o1;     // q,k: (B,H,T,64)
#pragma unroll
      for (int i = 0; i < 4; ++i)
#pragma unroll
        for (int j = 0; j < FN; ++j) {
          const int bt = col0 + j * 16 + lr;
          const int b = bt >> 10, t = bt & 1023;
          ushort4v pk;
#pragma unroll
          for (int r = 0; r < 4; ++r) pk[r] = f2bf(v[i][j][r]);
          *(ushort4v*)&dst[(((size_t)b * 8 + hh) * 1024 + t) * 64 + i * 16 + kg * 4] = pk;
        }
    } else {                               // v: (B,H,64,T)
#pragma unroll
      for (int i = 0; i < 4; ++i)
#pragma unroll
        for (int j = 0; j < FN; ++j) {
          const int bt = col0 + j * 16 + lr;
          const int b = bt >> 10, t = bt & 1023;
#pragma unroll
          for (int r = 0; r < 4; ++r) {
            const int dk = i * 16 + kg * 4 + r;
            o2[(((size_t)b * 8 + hh) * 64 + dk) * 1024 + t] = f2bf(v[i][j][r]);
          }
        }
    }
  } else if constexpr (MODE == 3) {  // ---- O-proj: +bias -> y1T (B,T,C) ----
#pragma unroll
    for (int i = 0; i < 4; ++i)
#pragma unroll
      for (int j = 0; j < FN; ++j) {
        const int bt = col0 + j * 16 + lr;
        const int c0 = wrow0 + i * 16 + kg * 4;
        ushort4v pk;
#pragma unroll
        for (int r = 0; r < 4; ++r) pk[r] = f2bf(acc[i][j][r] + bias[c0 + r]);
        *(ushort4v*)&o0[(size_t)bt * 512 + c0] = pk;
      }
  } else if constexpr (MODE == 4) {  // ---- conv1: relu(acc+b1)*mask -> h1pad ----
#pragma unroll
    for (int i = 0; i < 4; ++i) {
      const int r0 = wrow0 + i * 16 + kg * 4;
#pragma unroll
      for (int j = 0; j < FN; ++j) {
        const int bt = col0 + j * 16 + lr;
        const int b = bt >> 10, t = bt & 1023;
        const float mv = msk[(size_t)b * 1024 + t];
        ushort4v pk;
#pragma unroll
        for (int r = 0; r < 4; ++r)
          pk[r] = f2bf(fmaxf(acc[i][j][r] + bias[r0 + r], 0.f) * mv);
        *(ushort4v*)&o0[((size_t)(b * 1026 + t + 1)) * 2048 + r0] = pk;
      }
    }
  } else {                           // ---- conv2 split-K partial -> (B,T,C) ----
    u16* dst = (blockIdx.z == 0) ? o0 : o1;
#pragma unroll
    for (int i = 0; i < 4; ++i)
#pragma unroll
      for (int j = 0; j < FN; ++j) {
        const int bt = col0 + j * 16 + lr;
        const int b = bt >> 10, t = bt & 1023;
        const int c0 = wrow0 + i * 16 + kg * 4;
        const float mv = msk[(size_t)b * 1024 + t];
        ushort4v pk;
#pragma unroll
        for (int r = 0; r < 4; ++r) {
          const float bv = (blockIdx.z == 0) ? bias[c0 + r] : 0.f;
          pk[r] = f2bf((acc[i][j][r] + bv) * mv);
        }
        *(ushort4v*)&dst[(size_t)bt * 512 + c0] = pk;
      }
  }
}

// ---------------------------------------------------------------------------
// glue kernels
// ---------------------------------------------------------------------------
__global__ __launch_bounds__(256) void k_cvt(const float* __restrict__ in, u16* __restrict__ out, int n) {
  int i = blockIdx.x * 256 + threadIdx.x;
  if (i < n) out[i] = f2bf(in[i]);
}

__global__ __launch_bounds__(256) void k_repack_w1(const float* __restrict__ in, u16* __restrict__ out) {
  int i = blockIdx.x * 256 + threadIdx.x;          // over 2048*1536
  int f = i / 1536, rem = i % 1536;
  int kk = rem >> 9, c = rem & 511;                // out (F, KS, C)
  out[i] = f2bf(in[f * 1536 + c * 3 + kk]);
}

__global__ __launch_bounds__(256) void k_repack_w2(const float* __restrict__ in, u16* __restrict__ out) {
  int i = blockIdx.x * 256 + threadIdx.x;          // over 512*6144
  int c = i / 6144, rem = i % 6144;
  int kk = rem >> 11, f = rem & 2047;              // out (C, KS, F)
  out[i] = f2bf(in[c * 6144 + f * 3 + kk]);
}

__global__ __launch_bounds__(256) void k_bias_concat(const float* __restrict__ bq, const float* __restrict__ bk,
                                                     const float* __restrict__ bv, float* __restrict__ out) {
  int i = blockIdx.x * 256 + threadIdx.x;
  if (i < 512) out[i] = bq[i];
  else if (i < 1024) out[i] = bk[i - 512];
  else if (i < 1536) out[i] = bv[i - 1024];
}

__global__ __launch_bounds__(256) void k_rope_tables(float* __restrict__ ct, float* __restrict__ st) {
  int i = blockIdx.x * 256 + threadIdx.x;          // 1024*16
  int t = i >> 4, a = i & 15;
  float theta = powf(10000.f, -(float)a / 16.f);
  float ang = (float)t * theta;
  ct[i] = cosf(ang);
  st[i] = sinf(ang);
}

// pack attn_mask (B,1,T,T) fp32 -> bits; word i covers cols [i*32, i*32+32)
__global__ __launch_bounds__(256) void k_maskpack(const float* __restrict__ am, unsigned* __restrict__ mb) {
  int i = blockIdx.x * 256 + threadIdx.x;          // 8*1024*32 words
  const float* src = am + (size_t)i * 32;
  unsigned w = 0;
#pragma unroll
  for (int q = 0; q < 32; ++q) w |= (src[q] != 0.f) ? (1u << q) : 0u;
  mb[i] = w;
}

// zero pad rows (row 0 and 1025 of each batch) of a (B,1026,R) bf16 buffer
__global__ __launch_bounds__(256) void k_zrows(u16* __restrict__ p, int R) {
  const int b = blockIdx.x >> 1;
  const size_t row = (blockIdx.x & 1) ? 1025 : 0;
  u16* r = p + ((size_t)b * 1026 + row) * R;
  for (int i = threadIdx.x; i < R; i += 256) r[i] = 0;
}

// tiled fp32 (B,R,TT) -> bf16 (B,TT,R) transpose-convert, column mask applied
__global__ __launch_bounds__(256) void k_tcvt(const float* __restrict__ in, u16* __restrict__ out,
                                              const float* __restrict__ msk, int R, int TT) {
  __shared__ u16 tile[64][65];
  const int b = blockIdx.z;
  const int r0 = blockIdx.x * 64, t0 = blockIdx.y * 64;
  const int tx = threadIdx.x & 63, ty = threadIdx.x >> 6;
  const float mv = msk ? msk[(size_t)b * TT + t0 + tx] : 1.f;
  const float* ib = in + (size_t)b * R * TT;
#pragma unroll
  for (int rr = ty; rr < 64; rr += 4)
    tile[rr][tx] = f2bf(ib[(size_t)(r0 + rr) * TT + t0 + tx] * mv);
  __syncthreads();
  u16* ob = out + (size_t)b * TT * R;
#pragma unroll
  for (int tt = ty; tt < 64; tt += 4)
    ob[(size_t)(t0 + tt) * R + r0 + tx] = tile[tx][tt];
}

// LN1: one wave per (b,t) row of 512. r = xbT + y1T (both (B,T,C) bf16).
// Writes x2T (B,T,C) bf16 (LN out, residual for LN2) and x2p (B,1026,C) masked.
__global__ __launch_bounds__(256) void k_ln1(
    const u16* __restrict__ xbT, const u16* __restrict__ y1T,
    const float* __restrict__ xm, const float* __restrict__ g,
    const float* __restrict__ be, u16* __restrict__ x2T, u16* __restrict__ x2p)
{
  const int lane = threadIdx.x & 63, wv = threadIdx.x >> 6;
  const int row = blockIdx.x * 4 + wv;          // b*1024 + t
  const int b = row >> 10, t = row & 1023;
  const size_t base = (size_t)row * 512 + lane * 8;
  ushort8v ux = *(const ushort8v*)&xbT[base];
  ushort8v uy = *(const ushort8v*)&y1T[base];
  float v[8];
  float sum = 0.f, ss = 0.f;
#pragma unroll
  for (int q = 0; q < 8; ++q) {
    v[q] = bf2f(ux[q]) + bf2f(uy[q]);
    sum += v[q]; ss += v[q] * v[q];
  }
#pragma unroll
  for (int o = 32; o; o >>= 1) { sum += __shfl_xor(sum, o); ss += __shfl_xor(ss, o); }
  const float mean = sum * (1.f / 512.f);
  const float var  = ss * (1.f / 512.f) - mean * mean;
  const float rs   = rsqrtf(var + 1e-4f);
  const float m    = xm[(size_t)b * 1024 + t];
  ushort8v on, om;
#pragma unroll
  for (int q = 0; q < 8; ++q) {
    const int c = lane * 8 + q;
    const float nv = (v[q] - mean) * rs * g[c] + be[c];
    on[q] = f2bf(nv);
    om[q] = f2bf(nv * m);
  }
  *(ushort8v*)&x2T[base] = on;
  *(ushort8v*)&x2p[((size_t)(b * 1026 + t + 1)) * 512 + lane * 8] = om;
}

// LN2 stats: one wave per row; r = x2T + y2aT + y2bT; write (mean, rstd)
__global__ __launch_bounds__(256) void k_ln2_stats(
    const u16* __restrict__ x2T, const u16* __restrict__ y2a,
    const u16* __restrict__ y2b, float2* __restrict__ mr)
{
  const int lane = threadIdx.x & 63, wv = threadIdx.x >> 6;
  const int row = blockIdx.x * 4 + wv;
  const size_t base = (size_t)row * 512 + lane * 8;
  ushort8v u0 = *(const ushort8v*)&x2T[base];
  ushort8v u1 = *(const ushort8v*)&y2a[base];
  ushort8v u2 = *(const ushort8v*)&y2b[base];
  float sum = 0.f, ss = 0.f;
#pragma unroll
  for (int q = 0; q < 8; ++q) {
    const float v = bf2f(u0[q]) + bf2f(u1[q]) + bf2f(u2[q]);
    sum += v; ss += v * v;
  }
#pragma unroll
  for (int o = 32; o; o >>= 1) { sum += __shfl_xor(sum, o); ss += __shfl_xor(ss, o); }
  if (lane == 0) {
    const float mean = sum * (1.f / 512.f);
    const float var  = ss * (1.f / 512.f) - mean * mean;
    mr[row] = (float2){mean, rsqrtf(var + 1e-4f)};
  }
}

// LN2 write: normalize + transpose to out (B,C,T) fp32.
__global__ __launch_bounds__(256) void k_ln2_write(
    const u16* __restrict__ x2T, const u16* __restrict__ y2a,
    const u16* __restrict__ y2b, const float2* __restrict__ mr,
    const float* __restrict__ g, const float* __restrict__ be,
    float* __restrict__ out)
{
  __shared__ float tile[64][65];
  const int cc0 = blockIdx.x * 64, t0 = blockIdx.y * 64, b = blockIdx.z;
  const int tid = threadIdx.x;
  const int c4 = (tid & 15) * 4;
  const int tr = tid >> 4;
  float g4[4], b4[4];
#pragma unroll
  for (int q = 0; q < 4; ++q) { g4[q] = g[cc0 + c4 + q]; b4[q] = be[cc0 + c4 + q]; }
#pragma unroll
  for (int it = 0; it < 4; ++it) {
    const int tt = tr + it * 16;
    const int row = b * 1024 + t0 + tt;
    const size_t base = (size_t)row * 512 + cc0 + c4;
    ushort4v u0 = *(const ushort4v*)&x2T[base];
    ushort4v u1 = *(const ushort4v*)&y2a[base];
    ushort4v u2 = *(const ushort4v*)&y2b[base];
    const float2 s = mr[row];
#pragma unroll
    for (int q = 0; q < 4; ++q) {
      const float v = bf2f(u0[q]) + bf2f(u1[q]) + bf2f(u2[q]);
      tile[tt][c4 + q] = (v - s.x) * s.y * g4[q] + b4[q];
    }
  }
  __syncthreads();
  const int tx = tid & 63, cg = tid >> 6;
#pragma unroll
  for (int c = cg; c < 64; c += 4)
    out[((size_t)b * 512 + cc0 + c) * 1024 + t0 + tx] = tile[tx][c];
}

// ---------------------------------------------------------------------------
extern "C" void kernel_launch(void* const* d_in, const int* in_sizes, int n_in,
                              void* d_out, int out_size, void* d_ws, size_t ws_size,
                              hipStream_t stream) {
  (void)in_sizes; (void)n_in; (void)out_size; (void)ws_size;
  const float* x   = (const float*)d_in[0];
  const float* xm  = (const float*)d_in[1];
  const float* am  = (const float*)d_in[2];
  const float* wq  = (const float*)d_in[3];
  const float* bq  = (const float*)d_in[4];
  const float* wk  = (const float*)d_in[5];
  const float* bk  = (const float*)d_in[6];
  const float* wv  = (const float*)d_in[7];
  const float* bv  = (const float*)d_in[8];
  const float* wo  = (const float*)d_in[9];
  const float* bo  = (const float*)d_in[10];
  const float* w1  = (const float*)d_in[11];
  const float* b1  = (const float*)d_in[12];
  const float* w2  = (const float*)d_in[13];
  const float* b2  = (const float*)d_in[14];
  const float* g1  = (const float*)d_in[15];
  const float* be1 = (const float*)d_in[16];
  const float* g2  = (const float*)d_in[17];
  const float* be2 = (const float*)d_in[18];
  float* out = (float*)d_out;

  char* ws = (char*)d_ws;
  size_t off = 0;
  auto alloc = [&](size_t bytes) { char* p = ws + off; off += (bytes + 255) & ~(size_t)255; return p; };

  u16*   wqkv = (u16*)  alloc((size_t)1536 * 512 * 2);
  u16*   wob  = (u16*)  alloc((size_t)512 * 512 * 2);
  u16*   w1p  = (u16*)  alloc((size_t)2048 * 1536 * 2);
  u16*   w2p  = (u16*)  alloc((size_t)512 * 6144 * 2);
  float* bqkv = (float*)alloc(1536 * 4);
  float* ctab = (float*)alloc(1024 * 16 * 4);
  float* stab = (float*)alloc(1024 * 16 * 4);
  unsigned* mbits = (unsigned*)alloc((size_t)8 * 1024 * 32 * 4);
  float2* mr  = (float2*)alloc((size_t)8192 * 8);
  u16*   x2T  = (u16*)  alloc((size_t)8 * 1024 * 512 * 2);   // LN1 out (B,T,C)
  u16*   x2p  = (u16*)  alloc((size_t)8 * 1026 * 512 * 2);   // LN1 out masked, padded
  u16*   h1p  = (u16*)  alloc((size_t)8 * 1026 * 2048 * 2);  // conv1 out, padded (B,1026,F)
  u16*   y1T  = (u16*)  alloc((size_t)8 * 1024 * 512 * 2);   // attn out; conv2 partial A
  u16*   xbT  = (u16*)  alloc((size_t)8 * 1024 * 512 * 2);   // masked x^T (B,T,C)
  u16*   oT   = (u16*)  alloc((size_t)8 * 1024 * 512 * 2);   // attn O (B,T,C); conv2 partial B
  u16*   qkv3 = (u16*)  alloc((size_t)3 * 8 * 8 * 1024 * 64 * 2); // q,k,v

  u16* qb   = qkv3;
  u16* kb   = qkv3 + (size_t)8 * 8 * 1024 * 64;
  u16* vb   = kb   + (size_t)8 * 8 * 1024 * 64;
  u16* y2aT = y1T;   // conv2 partial A reuses y1T (dead after LN1)
  u16* y2bT = oT;    // conv2 partial B reuses oT  (dead after O-proj)

  dim3 blk(256);

  // weight/bias/table prep
  k_cvt<<<dim3(1024), blk, 0, stream>>>(wq, wqkv, 512 * 512);
  k_cvt<<<dim3(1024), blk, 0, stream>>>(wk, wqkv + 512 * 512, 512 * 512);
  k_cvt<<<dim3(1024), blk, 0, stream>>>(wv, wqkv + 2 * 512 * 512, 512 * 512);
  k_cvt<<<dim3(1024), blk, 0, stream>>>(wo, wob, 512 * 512);
  k_repack_w1<<<dim3(12288), blk, 0, stream>>>(w1, w1p);
  k_repack_w2<<<dim3(12288), blk, 0, stream>>>(w2, w2p);
  k_bias_concat<<<dim3(6), blk, 0, stream>>>(bq, bk, bv, bqkv);
  k_rope_tables<<<dim3(64), blk, 0, stream>>>(ctab, stab);
  k_maskpack<<<dim3(1024), blk, 0, stream>>>(am, mbits);
  k_zrows<<<dim3(16), blk, 0, stream>>>(x2p, 512);
  k_zrows<<<dim3(16), blk, 0, stream>>>(h1p, 2048);

  // x^T (masked, bf16)
  k_tcvt<<<dim3(8, 16, 8), blk, 0, stream>>>(x, xbT, xm, 512, 1024);

  // QKV projection + bias + rope + head scatter  (flat N=8192)
  k_cgemm<0, 128, 0><<<dim3(12, 64), blk, 0, stream>>>(
      wqkv, 512, xbT, 512, 512, qb, kb, vb, bqkv, ctab, stab, nullptr);

  // fused flash attention -> oT (B,T,C)
  k_fattn<<<dim3(8, 64), blk, 0, stream>>>(qb, kb, vb, mbits, oT);

  // y1 = wo o + bo -> y1T (B,T,C)
  k_cgemm<3, 64, 0><<<dim3(4, 128), blk, 0, stream>>>(
      wob, 512, oT, 512, 512, y1T, nullptr, nullptr, bo, nullptr, nullptr, nullptr);

  // LN1 rows -> x2T (residual) + x2p (masked, padded conv input)
  k_ln1<<<dim3(2048), blk, 0, stream>>>(xbT, y1T, xm, g1, be1, x2T, x2p);

  // conv path (tap-shifted padded activations)
  k_cgemm<4, 128, 512><<<dim3(16, 64), blk, 0, stream>>>(
      w1p, 1536, x2p, 0, 1536, h1p, nullptr, nullptr, b1, nullptr, nullptr, xm);
  // conv2: split-K x2 (K-slice 3072 each), T-major partials
  k_cgemm<5, 64, 2048><<<dim3(4, 128, 2), blk, 0, stream>>>(
      w2p, 6144, h1p, 0, 3072, y2aT, y2bT, nullptr, b2, nullptr, nullptr, xm);

  // LN2: stats then transpose-normalize -> out (B,C,T) fp32
  k_ln2_stats<<<dim3(2048), blk, 0, stream>>>(x2T, y2aT, y2bT, mr);
  k_ln2_write<<<dim3(8, 16, 8), blk, 0, stream>>>(x2T, y2aT, y2bT, mr, g2, be2, out);
}